// Round 10
// baseline (2450.125 us; speedup 1.0000x reference)
//
#include <hip/hip_runtime.h>
#include <hip/hip_bf16.h>
#include <math.h>

#define V 32000
#define B 32
#define E 64
#define H 256
#define T 128
#define NROW (B*T)     // 4096 rows, row = t*B + b
#define NC 128         // vocab cols per block (logits)
#define NVB (V/NC)     // 250

typedef __attribute__((ext_vector_type(8))) short bf16x8;
typedef __attribute__((ext_vector_type(4))) float f32x4;
typedef __attribute__((ext_vector_type(8))) unsigned short u16x8;

// ws layout (float offsets)
#define OFF_XS   0                          // xs fp32 [T*B][E]              1MB
#define OFF_XW   (OFF_XS + NROW*E)          // xwT bf16 8MB; WoT bf16 16MB aliases after recur
#define OFF_HB   (OFF_XW + NROW*4*H)        // hb bf16 [t*B+b][k]            2MB
#define OFF_PS   (OFF_HB + NROW*H/2)        // ps fp32 [NVB][NROW]           4MB
#define OFF_TL   (OFF_PS + NVB*NROW)        // tl fp32 [NROW]
#define OFF_UT   (OFF_TL + NROW)            // UT bf16 [(j*4+g)][k]          512KB
#define OFF_TGT  (OFF_UT + 4*H*H/2)         // tgtrow int [NROW]             16KB

static __device__ __forceinline__ unsigned short f2bf(float f) {
    union { float f; unsigned int u; } x; x.f = f;
    unsigned int r = x.u + 0x7fffu + ((x.u >> 16) & 1u);   // RNE
    return (unsigned short)(r >> 16);
}
static __device__ __forceinline__ float bf2f(unsigned short u) {
    union { unsigned int u; float f; } x; x.u = ((unsigned int)u) << 16; return x.f;
}
static __device__ __forceinline__ float sigmoidf_(float x) { return 1.f / (1.f + __expf(-x)); }
static __device__ __forceinline__ float tanhf_(float x)    { return 2.f / (1.f + __expf(-2.f * x)) - 1.f; }

// ------- kernel 1: embedding gather + target-row table + out zero -------------
__global__ void lstm_embed(const int* __restrict__ x, const float* __restrict__ emb,
                           const int* __restrict__ start, float* __restrict__ xs,
                           float* __restrict__ out, int* __restrict__ tgtrow) {
    int idx = blockIdx.x * 256 + threadIdx.x;
    if (idx == 0) out[0] = 0.f;               // zero accumulator each launch (graph-replay safe)
    if (idx < NROW) tgtrow[idx] = x[(idx & 31) * T + (idx >> 5)];   // tgt of row gr=t*32+b
    if (idx >= T * B * E) return;
    int t   = idx / (B * E);
    int rem = idx - t * (B * E);
    int b   = rem >> 6;
    int e   = rem & 63;
    int tok = (t == 0) ? start[0] : x[b * T + (t - 1)];
    xs[idx] = emb[tok * E + e];
}

// --- kernel 2: xwT[t][j][b][g] bf16 = (xs @ W_g + bias_g), block per t --------
__global__ __launch_bounds__(256) void lstm_xw(
        const float* __restrict__ xs, unsigned short* __restrict__ xwT,
        const float* __restrict__ Wi, const float* __restrict__ Wf,
        const float* __restrict__ Wog, const float* __restrict__ Wc,
        const float* __restrict__ bi, const float* __restrict__ bf,
        const float* __restrict__ bog, const float* __restrict__ bc) {
    __shared__ float xsl[32][65];
    const int t = blockIdx.x, tid = threadIdx.x;
    for (int i = tid; i < 32 * 64; i += 256) {
        int b = i >> 6, e = i & 63;
        xsl[b][e] = xs[(size_t)(t * 32 + b) * 64 + e];
    }
    __syncthreads();
    const int b = tid & 31, jg = tid >> 5;
    for (int jj = 0; jj < 32; ++jj) {
        const int j = jg * 32 + jj;
        float a0 = bi[j], a1 = bf[j], a2 = bog[j], a3 = bc[j];
        #pragma unroll 8
        for (int e = 0; e < E; ++e) {
            float xe = xsl[b][e];
            a0 += xe * Wi [e * H + j];
            a1 += xe * Wf [e * H + j];
            a2 += xe * Wog[e * H + j];
            a3 += xe * Wc [e * H + j];
        }
        ushort4 v;
        v.x = f2bf(a0); v.y = f2bf(a1); v.z = f2bf(a2); v.w = f2bf(a3);
        *(ushort4*)(xwT + ((size_t)(t * 256 + j) * 32 + b) * 4) = v;
    }
}

// ------ kernel 3: U_g[256][256] fp32 -> UT[(j*4+g)][k] bf16 (transposed) -------
__global__ __launch_bounds__(256) void lstm_ut(
        const float* __restrict__ Ui, const float* __restrict__ Uf,
        const float* __restrict__ Uog, const float* __restrict__ Uc,
        unsigned short* __restrict__ UT) {
    __shared__ unsigned short tle[64][65];
    const int g = blockIdx.z;
    const float* U = (g == 0) ? Ui : (g == 1) ? Uf : (g == 2) ? Uog : Uc;
    const int j0 = blockIdx.x * 64, k0 = blockIdx.y * 64;
    const int tid = threadIdx.x;
    for (int i = tid; i < 64 * 64; i += 256) {
        int kk = i >> 6, jj = i & 63;
        tle[kk][jj] = f2bf(U[(size_t)(k0 + kk) * H + j0 + jj]);
    }
    __syncthreads();
    for (int c = tid; c < 512; c += 256) {
        int jj = c >> 3, kc = c & 7;
        u16x8 v;
        #pragma unroll
        for (int e = 0; e < 8; ++e) v[e] = tle[kc * 8 + e][jj];
        *(u16x8*)(UT + ((size_t)(j0 + jj) * 4 + g) * H + k0 + kc * 8) = v;
    }
}

// ---- kernel 4: recurrence — ONE 512-thread block, MFMA, U in RF+L2-stream ----
// 8 waves; wave w owns gate-cols [w*128, w*128+128) = 8 col-frags (cf) of 16.
// cf 0,1 A-frags pinned in VGPRs for all T steps; cf 2..7 streamed from L2
// (UT is 512KB -> L2-resident on this CU's XCD after first step).
// Gate-quad-in-lane (verified r6/r8): lane(lr,lg) reg r of acc[cf][bt] =
// gate r (i,f,o,cbar) of j=w*32+cf*4+lg, batch bt*16+lr -> pointwise LSTM
// in-register, c-state in c_[8][2]. h double-buffered in XOR-swizzled LDS
// (r4/r5 pattern); xw quads prefetched at step start (HBM latency hidden).
// One __syncthreads per step.
__global__ __launch_bounds__(512, 2) void lstm_recur1(
        const unsigned short* __restrict__ xwT, const unsigned short* __restrict__ UT,
        unsigned short* __restrict__ hb) {
    __shared__ char h_s[2][16384];
    const int tid = threadIdx.x;
    const int lane = tid & 63, w = tid >> 6;
    const int lr = lane & 15, lg = lane >> 4;
    const int swz = (lr & 7) << 4;

    const unsigned short* ubase = UT + (size_t)(w * 128 + lr) * H + lg * 8;
    bf16x8 A0[8], A1[8];                       // RF-resident A frags (cf 0,1)
    #pragma unroll
    for (int kt = 0; kt < 8; ++kt) A0[kt] = *(const bf16x8*)(ubase + kt * 32);
    #pragma unroll
    for (int kt = 0; kt < 8; ++kt) A1[kt] = *(const bf16x8*)(ubase + 16 * H + kt * 32);

    float c_[8][2] = {};

    // ---- t = 0: gates = xw only (h0 = c0 = 0) ----
    {
        char* hsW = h_s[1];
        #pragma unroll
        for (int cf = 0; cf < 8; ++cf) {
            const int j_ = w * 32 + cf * 4 + lg;
            const unsigned short* xp = xwT + (size_t)j_ * 32 * 4;
            #pragma unroll
            for (int bt = 0; bt < 2; ++bt) {
                ushort4 xa = *(const ushort4*)(xp + (bt * 16 + lr) * 4);
                float pi = bf2f(xa.x), po = bf2f(xa.z), pc = bf2f(xa.w);
                float cc = sigmoidf_(pi) * tanhf_(pc);
                c_[cf][bt] = cc;
                *(unsigned short*)(hsW + (bt * 16 + lr) * 512 + ((2 * j_) ^ swz))
                    = f2bf(sigmoidf_(po) * tanhf_(cc));
            }
        }
        __syncthreads();
        const int oo = tid * 32;
        #pragma unroll
        for (int hh = 0; hh < 2; ++hh) {
            int o2 = oo + hh * 16, row = o2 >> 9, col = o2 & 511;
            *(uint4*)((char*)hb + o2) =
                *(const uint4*)(h_s[1] + row * 512 + (col ^ ((row & 7) << 4)));
        }
    }

    #pragma unroll 1
    for (int t = 1; t < T; ++t) {
        const char* hsR = h_s[t & 1];
        char*       hsW = h_s[(t + 1) & 1];

        // prefetch this step's xw quads (16 x 8B; consumed ~2us later)
        ushort4 xq[8][2];
        {
            const unsigned short* xb = xwT + (size_t)t * 256 * 32 * 4;
            #pragma unroll
            for (int cf = 0; cf < 8; ++cf) {
                const int j_ = w * 32 + cf * 4 + lg;
                #pragma unroll
                for (int bt = 0; bt < 2; ++bt)
                    xq[cf][bt] = *(const ushort4*)(xb + ((size_t)j_ * 32 + bt * 16 + lr) * 4);
            }
        }

        f32x4 ac[8][2] = {};
        #pragma unroll
        for (int kt = 0; kt < 8; ++kt) {
            const int cb = (kt * 64 + lg * 16) ^ swz;
            bf16x8 B0 = *(const bf16x8*)(hsR + lr * 512 + cb);
            bf16x8 B1 = *(const bf16x8*)(hsR + (16 + lr) * 512 + cb);
            ac[0][0] = __builtin_amdgcn_mfma_f32_16x16x32_bf16(A0[kt], B0, ac[0][0], 0, 0, 0);
            ac[0][1] = __builtin_amdgcn_mfma_f32_16x16x32_bf16(A0[kt], B1, ac[0][1], 0, 0, 0);
            ac[1][0] = __builtin_amdgcn_mfma_f32_16x16x32_bf16(A1[kt], B0, ac[1][0], 0, 0, 0);
            ac[1][1] = __builtin_amdgcn_mfma_f32_16x16x32_bf16(A1[kt], B1, ac[1][1], 0, 0, 0);
            #pragma unroll
            for (int cf = 2; cf < 8; ++cf) {
                bf16x8 Sf = *(const bf16x8*)(ubase + (size_t)cf * 16 * H + kt * 32);
                ac[cf][0] = __builtin_amdgcn_mfma_f32_16x16x32_bf16(Sf, B0, ac[cf][0], 0, 0, 0);
                ac[cf][1] = __builtin_amdgcn_mfma_f32_16x16x32_bf16(Sf, B1, ac[cf][1], 0, 0, 0);
            }
        }

        #pragma unroll
        for (int cf = 0; cf < 8; ++cf) {
            const int j_ = w * 32 + cf * 4 + lg;
            #pragma unroll
            for (int bt = 0; bt < 2; ++bt) {
                float pi = bf2f(xq[cf][bt].x) + ac[cf][bt][0];
                float pf = bf2f(xq[cf][bt].y) + ac[cf][bt][1];
                float po = bf2f(xq[cf][bt].z) + ac[cf][bt][2];
                float pc = bf2f(xq[cf][bt].w) + ac[cf][bt][3];
                float cc = sigmoidf_(pf) * c_[cf][bt] + sigmoidf_(pi) * tanhf_(pc);
                c_[cf][bt] = cc;
                *(unsigned short*)(hsW + (bt * 16 + lr) * 512 + ((2 * j_) ^ swz))
                    = f2bf(sigmoidf_(po) * tanhf_(cc));
            }
        }
        __syncthreads();
        const int oo = tid * 32;
        #pragma unroll
        for (int hh = 0; hh < 2; ++hh) {
            int o2 = oo + hh * 16, row = o2 >> 9, col = o2 & 511;
            *(uint4*)((char*)hb + (size_t)t * 16384 + o2) =
                *(const uint4*)(hsW + row * 512 + (col ^ ((row & 7) << 4)));
        }
    }
}

// -------- kernel 5: Wo [K=256][V] fp32  ->  WoT [V][K=256] bf16 (transpose) ---
__global__ __launch_bounds__(256) void lstm_wot(const float* __restrict__ Wo,
                                                unsigned short* __restrict__ WoT) {
    __shared__ unsigned short tle[64][65];
    const int n0 = blockIdx.x * 64, k0 = blockIdx.y * 64;
    const int tid = threadIdx.x;
    for (int i = tid; i < 64 * 64; i += 256) {
        int kk = i >> 6, nn = i & 63;
        tle[kk][nn] = f2bf(Wo[(size_t)(k0 + kk) * V + n0 + nn]);
    }
    __syncthreads();
    for (int c = tid; c < 512; c += 256) {
        int nn = c >> 3, kc = c & 7;
        u16x8 v;
        #pragma unroll
        for (int e = 0; e < 8; ++e) v[e] = tle[kc * 8 + e][nn];
        *(u16x8*)(WoT + (size_t)(n0 + nn) * H + k0 + kc * 8) = v;
    }
}

// ---- kernel 6: logits GEMM, B-tile in VGPRs, r0-loop, max-free fused softmax -
__global__ __launch_bounds__(512, 2) void lstm_logits_mfma(
        const unsigned short* __restrict__ hb, const unsigned short* __restrict__ WoT,
        const float* __restrict__ bo, const int* __restrict__ tgtrow,
        float* __restrict__ ps, float* __restrict__ tl) {
    __shared__ char a_s[65536];          // A tile 64KB, XOR-swizzled 512B rows
    __shared__ char b_s[65536];          // B stage 64KB
    __shared__ float s_red[4][128];      // per-colwave row sums
    __shared__ int   tgt_l[128];
    const int tid = threadIdx.x, lane = tid & 63, wid = tid >> 6;
    const int wr = wid >> 2, wc = wid & 3;          // 2 row-halves x 4 col-quarters
    const int lr = lane & 15, lg = lane >> 4;
    const int swz = lr & 7;
    const int vb = blockIdx.x * NC;

    {
        const uint4* srcB = (const uint4*)(WoT + (size_t)vb * H);
        for (int c = tid; c < 4096; c += 512) {
            int row = c >> 5, c16 = c & 31;
            *(uint4*)(b_s + row * 512 + ((c16 ^ (row & 7)) << 4)) = srcB[c];
        }
    }
    __syncthreads();
    bf16x8 Bf[2][8];
    {
        const char* bBase = b_s + (wc * 32 + lr) * 512;
        #pragma unroll
        for (int nf = 0; nf < 2; ++nf)
            #pragma unroll
            for (int ks = 0; ks < 8; ++ks)
                Bf[nf][ks] = *(const bf16x8*)(bBase + nf * 16 * 512 + (((ks * 4 + lg) ^ swz) << 4));
    }
    float bocol[2] = { bo[vb + wc * 32 + lr], bo[vb + wc * 32 + 16 + lr] };

    for (int rb = 0; rb < NROW / 128; ++rb) {
        {
            const uint4* srcA = (const uint4*)(hb + (size_t)rb * 128 * H);
            for (int c = tid; c < 4096; c += 512) {
                int row = c >> 5, c16 = c & 31;
                *(uint4*)(a_s + row * 512 + ((c16 ^ (row & 7)) << 4)) = srcA[c];
            }
            if (tid < 128) tgt_l[tid] = tgtrow[rb * 128 + tid];
        }
        __syncthreads();

        f32x4 acc[4][2] = {};
        const char* aBase = a_s + (wr * 64 + lr) * 512;
        #pragma unroll
        for (int ks = 0; ks < 8; ++ks) {
            bf16x8 a[4];
            #pragma unroll
            for (int mf = 0; mf < 4; ++mf)
                a[mf] = *(const bf16x8*)(aBase + mf * 16 * 512 + (((ks * 4 + lg) ^ swz) << 4));
            #pragma unroll
            for (int mf = 0; mf < 4; ++mf)
                #pragma unroll
                for (int nf = 0; nf < 2; ++nf)
                    acc[mf][nf] = __builtin_amdgcn_mfma_f32_16x16x32_bf16(a[mf], Bf[nf][ks], acc[mf][nf], 0, 0, 0);
        }

        const int col0 = vb + wc * 32 + lr, col1 = col0 + 16;
        #pragma unroll
        for (int mf = 0; mf < 4; ++mf)
            #pragma unroll
            for (int r = 0; r < 4; ++r) {
                const int row_l = wr * 64 + mf * 16 + lg * 4 + r;
                float v0 = acc[mf][0][r] + bocol[0];
                float v1 = acc[mf][1][r] + bocol[1];
                const int tg = tgt_l[row_l];
                if (tg == col0) tl[rb * 128 + row_l] = v0;
                if (tg == col1) tl[rb * 128 + row_l] = v1;
                float e = __expf(v0) + __expf(v1);
                e += __shfl_xor(e, 1); e += __shfl_xor(e, 2);
                e += __shfl_xor(e, 4); e += __shfl_xor(e, 8);
                if (lr == 0) s_red[wc][row_l] = e;
            }
        __syncthreads();
        if (tid < 128)
            ps[(size_t)blockIdx.x * NROW + rb * 128 + tid] =
                s_red[0][tid] + s_red[1][tid] + s_red[2][tid] + s_red[3][tid];
        __syncthreads();
    }
}

// ---------------- kernel 7: combine chunk sums, reduce NLL --------------------
__global__ __launch_bounds__(256) void lstm_lse(
        const float* __restrict__ ps, const float* __restrict__ tl,
        float* __restrict__ out) {
    const int row = blockIdx.x * 256 + threadIdx.x;
    float s = 0.f;
    for (int c = 0; c < NVB; ++c) s += ps[(size_t)c * NROW + row];
    float nll = logf(s) - tl[row];
    __shared__ float red[256];
    red[threadIdx.x] = nll;
    __syncthreads();
    for (int off = 128; off > 0; off >>= 1) {
        if (threadIdx.x < off) red[threadIdx.x] += red[threadIdx.x + off];
        __syncthreads();
    }
    if (threadIdx.x == 0) atomicAdd(out, red[0]);
}

extern "C" void kernel_launch(void* const* d_in, const int* in_sizes, int n_in,
                              void* d_out, int out_size, void* d_ws, size_t ws_size,
                              hipStream_t stream) {
    const int*   x     = (const int*)d_in[0];
    const float* emb   = (const float*)d_in[1];
    const float* Wi    = (const float*)d_in[2];
    const float* Ui    = (const float*)d_in[3];
    const float* bi    = (const float*)d_in[4];
    const float* Wf    = (const float*)d_in[5];
    const float* Uf    = (const float*)d_in[6];
    const float* bf    = (const float*)d_in[7];
    const float* Wog   = (const float*)d_in[8];
    const float* Uog   = (const float*)d_in[9];
    const float* bog   = (const float*)d_in[10];
    const float* Wc    = (const float*)d_in[11];
    const float* Uc    = (const float*)d_in[12];
    const float* bc    = (const float*)d_in[13];
    const float* Wo    = (const float*)d_in[14];
    const float* bo    = (const float*)d_in[15];
    const int*   start = (const int*)d_in[16];
    float* ws  = (float*)d_ws;
    float* out = (float*)d_out;

    float*          xs   = ws + OFF_XS;
    unsigned short* xwT  = (unsigned short*)(ws + OFF_XW);
    unsigned short* WoT  = (unsigned short*)(ws + OFF_XW);   // aliases xwT (dead after recur)
    unsigned short* hbf  = (unsigned short*)(ws + OFF_HB);
    float*          psB  = ws + OFF_PS;
    float*          tlB  = ws + OFF_TL;
    unsigned short* UT   = (unsigned short*)(ws + OFF_UT);
    int*            tgtr = (int*)(ws + OFF_TGT);

    lstm_embed <<<(T * B * E + 255) / 256, 256, 0, stream>>>(x, emb, start, xs, out, tgtr);
    lstm_xw    <<<T, 256, 0, stream>>>(xs, xwT, Wi, Wf, Wog, Wc, bi, bf, bog, bc);
    lstm_ut    <<<dim3(H / 64, H / 64, 4), 256, 0, stream>>>(Ui, Uf, Uog, Uc, UT);
    lstm_recur1<<<1, 512, 0, stream>>>(xwT, UT, hbf);
    lstm_wot   <<<dim3(V / 64, H / 64), 256, 0, stream>>>(Wo, WoT);
    lstm_logits_mfma<<<NVB, 512, 0, stream>>>(hbf, WoT, bo, tgtr, psB, tlB);
    lstm_lse   <<<NROW / 256, 256, 0, stream>>>(psB, tlB, out);
}

// Round 11
// 506.181 us; speedup vs baseline: 4.8404x; 4.8404x over previous
//
#include <hip/hip_runtime.h>
#include <hip/hip_bf16.h>
#include <math.h>

#define V 32000
#define B 32
#define E 64
#define H 256
#define T 128
#define NROW (B*T)     // 4096 rows, row = t*B + b
#define NC 128         // vocab cols per block (logits)
#define NVB (V/NC)     // 250

typedef __attribute__((ext_vector_type(8))) short bf16x8;
typedef __attribute__((ext_vector_type(4))) float f32x4;
typedef __attribute__((ext_vector_type(8))) unsigned short u16x8;

// ws layout (float offsets)
#define OFF_XS   0                          // xs fp32 [T*B][E]              1MB
#define OFF_XW   (OFF_XS + NROW*E)          // xwq bf16 8MB; WoT bf16 16MB aliases after recur
#define OFF_HB   (OFF_XW + NROW*4*H)        // hb bf16 [t*B+b][k]            2MB
#define OFF_PS   (OFF_HB + NROW*H/2)        // ps fp32 [NVB][NROW]           4MB
#define OFF_TL   (OFF_PS + NVB*NROW)        // tl fp32 [NROW]
#define OFF_U8   (OFF_TL + NROW)            // UQ8 i8 [k4][j][g*4+kk]        256KB
#define OFF_SC   (OFF_U8 + H*H)             // per-gate scales, 4 floats
#define OFF_TGT  (OFF_SC + 16)              // tgtrow int [NROW]             16KB

static __device__ __forceinline__ unsigned short f2bf(float f) {
    union { float f; unsigned int u; } x; x.f = f;
    unsigned int r = x.u + 0x7fffu + ((x.u >> 16) & 1u);   // RNE
    return (unsigned short)(r >> 16);
}
static __device__ __forceinline__ float bf2f(unsigned short u) {
    union { unsigned int u; float f; } x; x.u = ((unsigned int)u) << 16; return x.f;
}
static __device__ __forceinline__ float sigmoidf_(float x) { return 1.f / (1.f + __expf(-x)); }
static __device__ __forceinline__ float tanhf_(float x)    { return 2.f / (1.f + __expf(-2.f * x)) - 1.f; }

#if defined(__has_builtin)
#if __has_builtin(__builtin_amdgcn_sdot4)
#define HAVE_SDOT4 1
#endif
#endif
static __device__ __forceinline__ int dot4i8(unsigned int a, unsigned int b, int c) {
#ifdef HAVE_SDOT4
    return __builtin_amdgcn_sdot4((int)a, (int)b, c, false);
#else
    c += (int)(char)(a)       * (int)(char)(b);
    c += (int)(char)(a >> 8)  * (int)(char)(b >> 8);
    c += (int)(char)(a >> 16) * (int)(char)(b >> 16);
    c += (int)(char)(a >> 24) * (int)(char)(b >> 24);
    return c;
#endif
}

// ------- kernel 1: embedding gather + target-row table + out zero -------------
__global__ void lstm_embed(const int* __restrict__ x, const float* __restrict__ emb,
                           const int* __restrict__ start, float* __restrict__ xs,
                           float* __restrict__ out, int* __restrict__ tgtrow) {
    int idx = blockIdx.x * 256 + threadIdx.x;
    if (idx == 0) out[0] = 0.f;               // zero accumulator each launch (graph-replay safe)
    if (idx < NROW) tgtrow[idx] = x[(idx & 31) * T + (idx >> 5)];   // tgt of row gr=t*32+b
    if (idx >= T * B * E) return;
    int t   = idx / (B * E);
    int rem = idx - t * (B * E);
    int b   = rem >> 6;
    int e   = rem & 63;
    int tok = (t == 0) ? start[0] : x[b * T + (t - 1)];
    xs[idx] = emb[tok * E + e];
}

// --- kernel 2: xwq[t*32+b][j][g] bf16 = (xs @ W_g + bias_g), block per t ------
__global__ __launch_bounds__(256) void lstm_xw(
        const float* __restrict__ xs, unsigned short* __restrict__ xwq,
        const float* __restrict__ Wi, const float* __restrict__ Wf,
        const float* __restrict__ Wog, const float* __restrict__ Wc,
        const float* __restrict__ bi, const float* __restrict__ bf,
        const float* __restrict__ bog, const float* __restrict__ bc) {
    __shared__ float xsl[32][65];
    const int t = blockIdx.x, tid = threadIdx.x;
    for (int i = tid; i < 32 * 64; i += 256) {
        int b = i >> 6, e = i & 63;
        xsl[b][e] = xs[(size_t)(t * 32 + b) * 64 + e];
    }
    __syncthreads();
    const int b = tid & 31, jg = tid >> 5;
    for (int jj = 0; jj < 32; ++jj) {
        const int j = jg * 32 + jj;
        float a0 = bi[j], a1 = bf[j], a2 = bog[j], a3 = bc[j];
        #pragma unroll 8
        for (int e = 0; e < E; ++e) {
            float xe = xsl[b][e];
            a0 += xe * Wi [e * H + j];
            a1 += xe * Wf [e * H + j];
            a2 += xe * Wog[e * H + j];
            a3 += xe * Wc [e * H + j];
        }
        ushort4 v;
        v.x = f2bf(a0); v.y = f2bf(a1); v.z = f2bf(a2); v.w = f2bf(a3);
        *(ushort4*)(xwq + ((size_t)(t * 32 + b) * 256 + j) * 4) = v;
    }
}

// ---- kernel 3: per-gate absmax of U (one block per gate, no atomics) ---------
__global__ __launch_bounds__(256) void lstm_umax(
        const float* __restrict__ Ui, const float* __restrict__ Uf,
        const float* __restrict__ Uog, const float* __restrict__ Uc,
        float* __restrict__ sc) {
    const int g = blockIdx.x;
    const float* U = (g == 0) ? Ui : (g == 1) ? Uf : (g == 2) ? Uog : Uc;
    float m = 0.f;
    for (int i = threadIdx.x; i < H * H; i += 256) m = fmaxf(m, fabsf(U[i]));
    __shared__ float red[256];
    red[threadIdx.x] = m;
    __syncthreads();
    for (int off = 128; off > 0; off >>= 1) {
        if (threadIdx.x < off) red[threadIdx.x] = fmaxf(red[threadIdx.x], red[threadIdx.x + off]);
        __syncthreads();
    }
    if (threadIdx.x == 0) sc[g] = fmaxf(red[0], 1e-20f);
}

// ---- kernel 4: U_g fp32 -> UQ8[k4][j] 16B = {gate g dword: bytes k4*4+0..3} --
__global__ __launch_bounds__(256) void lstm_uq8(
        const float* __restrict__ Ui, const float* __restrict__ Uf,
        const float* __restrict__ Uog, const float* __restrict__ Uc,
        const float* __restrict__ sc, unsigned int* __restrict__ UQ8) {
    const int idx = blockIdx.x * 256 + threadIdx.x;   // 64 k4 x 256 j
    const int k4 = idx >> 8, j = idx & 255;
    float inv[4] = { 127.f / sc[0], 127.f / sc[1], 127.f / sc[2], 127.f / sc[3] };
    const float* Ug[4] = { Ui, Uf, Uog, Uc };
    uint4 out;
    unsigned int* op = (unsigned int*)&out;
    #pragma unroll
    for (int g = 0; g < 4; ++g) {
        unsigned int w = 0;
        #pragma unroll
        for (int kk = 0; kk < 4; ++kk) {
            float v = Ug[g][(size_t)(k4 * 4 + kk) * H + j];
            int q = __float2int_rn(v * inv[g]);
            q = q > 127 ? 127 : (q < -127 ? -127 : q);
            w |= ((unsigned int)(q & 255)) << (kk * 8);
        }
        op[g] = w;
    }
    *(uint4*)(UQ8 + (size_t)idx * 4) = out;
}

// ---- kernel 5: recurrence — 32 independent blocks (1/batch row), i8 dot4 -----
// 1024 threads = 16 waves (4/SIMD). Thread (j = tid&255, q = tid>>8) computes
// the 4 gate partial dots of hidden unit j over k-quarter q (64 k) via
// v_dot4_i32_i8 on int8 U (256KB/step streamed from XCD L2, coalesced 1KB/wave
// per load) x int8 h (LDS, broadcast). 16KB LDS int4 reduce across quarters,
// then threads 0..255 do the pointwise LSTM (c in register), write h as bf16
// to hb and as int8 to the LDS ping-pong buffer. No inter-block communication.
__global__ __launch_bounds__(1024) void lstm_recur_i8(
        const unsigned short* __restrict__ xwq, const uint4* __restrict__ UQ8,
        const float* __restrict__ sc, unsigned short* __restrict__ hb) {
    __shared__ unsigned int hq8[2][64];     // int8 h, ping-pong, 4 k per dword
    __shared__ int4 red[4][256];            // per-quarter gate sums
    const int b = blockIdx.x, tid = threadIdx.x;
    const int j = tid & 255, q = tid >> 8;
    const float f0 = sc[0] * (1.f / 16129.f), f1 = sc[1] * (1.f / 16129.f);
    const float f2 = sc[2] * (1.f / 16129.f), f3 = sc[3] * (1.f / 16129.f);
    float c_ = 0.f;

    for (int t = 0; t < T; ++t) {
        if (t > 0) {
            const uint4* up = UQ8 + (size_t)(q * 16) * 256 + j;
            const unsigned int* hrow = hq8[t & 1] + q * 16;
            int a0 = 0, a1 = 0, a2 = 0, a3 = 0;
            #pragma unroll
            for (int m = 0; m < 16; ++m) {
                uint4 u = up[(size_t)m * 256];
                unsigned int hv = hrow[m];
                a0 = dot4i8(u.x, hv, a0);
                a1 = dot4i8(u.y, hv, a1);
                a2 = dot4i8(u.z, hv, a2);
                a3 = dot4i8(u.w, hv, a3);
            }
            red[q][j] = make_int4(a0, a1, a2, a3);
        }
        __syncthreads();
        if (tid < 256) {
            ushort4 xw = *(const ushort4*)(xwq + ((size_t)(t * 32 + b) * 256 + j) * 4);
            float pi = bf2f(xw.x), pf = bf2f(xw.y), po = bf2f(xw.z), pc = bf2f(xw.w);
            if (t > 0) {
                int4 r0 = red[0][j], r1 = red[1][j], r2 = red[2][j], r3 = red[3][j];
                pi += (float)(r0.x + r1.x + r2.x + r3.x) * f0;
                pf += (float)(r0.y + r1.y + r2.y + r3.y) * f1;
                po += (float)(r0.z + r1.z + r2.z + r3.z) * f2;
                pc += (float)(r0.w + r1.w + r2.w + r3.w) * f3;
            }
            c_ = sigmoidf_(pf) * c_ + sigmoidf_(pi) * tanhf_(pc);
            float h = sigmoidf_(po) * tanhf_(c_);
            hb[(size_t)(t * B + b) * H + j] = f2bf(h);
            ((char*)hq8[(t + 1) & 1])[j] = (char)__float2int_rn(h * 127.f);
        }
        __syncthreads();
    }
}

// -------- kernel 6: Wo [K=256][V] fp32  ->  WoT [V][K=256] bf16 (transpose) ---
__global__ __launch_bounds__(256) void lstm_wot(const float* __restrict__ Wo,
                                                unsigned short* __restrict__ WoT) {
    __shared__ unsigned short tle[64][65];
    const int n0 = blockIdx.x * 64, k0 = blockIdx.y * 64;
    const int tid = threadIdx.x;
    for (int i = tid; i < 64 * 64; i += 256) {
        int kk = i >> 6, nn = i & 63;
        tle[kk][nn] = f2bf(Wo[(size_t)(k0 + kk) * V + n0 + nn]);
    }
    __syncthreads();
    for (int c = tid; c < 512; c += 256) {
        int nn = c >> 3, kc = c & 7;
        u16x8 v;
        #pragma unroll
        for (int e = 0; e < 8; ++e) v[e] = tle[kc * 8 + e][nn];
        *(u16x8*)(WoT + (size_t)(n0 + nn) * H + k0 + kc * 8) = v;
    }
}

// ---- kernel 7: logits GEMM, B-tile in VGPRs, r0-loop, max-free fused softmax -
__global__ __launch_bounds__(512, 2) void lstm_logits_mfma(
        const unsigned short* __restrict__ hb, const unsigned short* __restrict__ WoT,
        const float* __restrict__ bo, const int* __restrict__ tgtrow,
        float* __restrict__ ps, float* __restrict__ tl) {
    __shared__ char a_s[65536];          // A tile 64KB, XOR-swizzled 512B rows
    __shared__ char b_s[65536];          // B stage 64KB
    __shared__ float s_red[4][128];      // per-colwave row sums
    __shared__ int   tgt_l[128];
    const int tid = threadIdx.x, lane = tid & 63, wid = tid >> 6;
    const int wr = wid >> 2, wc = wid & 3;          // 2 row-halves x 4 col-quarters
    const int lr = lane & 15, lg = lane >> 4;
    const int swz = lr & 7;
    const int vb = blockIdx.x * NC;

    {
        const uint4* srcB = (const uint4*)(WoT + (size_t)vb * H);
        for (int c = tid; c < 4096; c += 512) {
            int row = c >> 5, c16 = c & 31;
            *(uint4*)(b_s + row * 512 + ((c16 ^ (row & 7)) << 4)) = srcB[c];
        }
    }
    __syncthreads();
    bf16x8 Bf[2][8];
    {
        const char* bBase = b_s + (wc * 32 + lr) * 512;
        #pragma unroll
        for (int nf = 0; nf < 2; ++nf)
            #pragma unroll
            for (int ks = 0; ks < 8; ++ks)
                Bf[nf][ks] = *(const bf16x8*)(bBase + nf * 16 * 512 + (((ks * 4 + lg) ^ swz) << 4));
    }
    float bocol[2] = { bo[vb + wc * 32 + lr], bo[vb + wc * 32 + 16 + lr] };

    for (int rb = 0; rb < NROW / 128; ++rb) {
        {
            const uint4* srcA = (const uint4*)(hb + (size_t)rb * 128 * H);
            for (int c = tid; c < 4096; c += 512) {
                int row = c >> 5, c16 = c & 31;
                *(uint4*)(a_s + row * 512 + ((c16 ^ (row & 7)) << 4)) = srcA[c];
            }
            if (tid < 128) tgt_l[tid] = tgtrow[rb * 128 + tid];
        }
        __syncthreads();

        f32x4 acc[4][2] = {};
        const char* aBase = a_s + (wr * 64 + lr) * 512;
        #pragma unroll
        for (int ks = 0; ks < 8; ++ks) {
            bf16x8 a[4];
            #pragma unroll
            for (int mf = 0; mf < 4; ++mf)
                a[mf] = *(const bf16x8*)(aBase + mf * 16 * 512 + (((ks * 4 + lg) ^ swz) << 4));
            #pragma unroll
            for (int mf = 0; mf < 4; ++mf)
                #pragma unroll
                for (int nf = 0; nf < 2; ++nf)
                    acc[mf][nf] = __builtin_amdgcn_mfma_f32_16x16x32_bf16(a[mf], Bf[nf][ks], acc[mf][nf], 0, 0, 0);
        }

        const int col0 = vb + wc * 32 + lr, col1 = col0 + 16;
        #pragma unroll
        for (int mf = 0; mf < 4; ++mf)
            #pragma unroll
            for (int r = 0; r < 4; ++r) {
                const int row_l = wr * 64 + mf * 16 + lg * 4 + r;
                float v0 = acc[mf][0][r] + bocol[0];
                float v1 = acc[mf][1][r] + bocol[1];
                const int tg = tgt_l[row_l];
                if (tg == col0) tl[rb * 128 + row_l] = v0;
                if (tg == col1) tl[rb * 128 + row_l] = v1;
                float e = __expf(v0) + __expf(v1);
                e += __shfl_xor(e, 1); e += __shfl_xor(e, 2);
                e += __shfl_xor(e, 4); e += __shfl_xor(e, 8);
                if (lr == 0) s_red[wc][row_l] = e;
            }
        __syncthreads();
        if (tid < 128)
            ps[(size_t)blockIdx.x * NROW + rb * 128 + tid] =
                s_red[0][tid] + s_red[1][tid] + s_red[2][tid] + s_red[3][tid];
        __syncthreads();
    }
}

// ---------------- kernel 8: combine chunk sums, reduce NLL --------------------
__global__ __launch_bounds__(256) void lstm_lse(
        const float* __restrict__ ps, const float* __restrict__ tl,
        float* __restrict__ out) {
    const int row = blockIdx.x * 256 + threadIdx.x;
    float s = 0.f;
    for (int c = 0; c < NVB; ++c) s += ps[(size_t)c * NROW + row];
    float nll = logf(s) - tl[row];
    __shared__ float red[256];
    red[threadIdx.x] = nll;
    __syncthreads();
    for (int off = 128; off > 0; off >>= 1) {
        if (threadIdx.x < off) red[threadIdx.x] += red[threadIdx.x + off];
        __syncthreads();
    }
    if (threadIdx.x == 0) atomicAdd(out, red[0]);
}

extern "C" void kernel_launch(void* const* d_in, const int* in_sizes, int n_in,
                              void* d_out, int out_size, void* d_ws, size_t ws_size,
                              hipStream_t stream) {
    const int*   x     = (const int*)d_in[0];
    const float* emb   = (const float*)d_in[1];
    const float* Wi    = (const float*)d_in[2];
    const float* Ui    = (const float*)d_in[3];
    const float* bi    = (const float*)d_in[4];
    const float* Wf    = (const float*)d_in[5];
    const float* Uf    = (const float*)d_in[6];
    const float* bf    = (const float*)d_in[7];
    const float* Wog   = (const float*)d_in[8];
    const float* Uog   = (const float*)d_in[9];
    const float* bog   = (const float*)d_in[10];
    const float* Wc    = (const float*)d_in[11];
    const float* Uc    = (const float*)d_in[12];
    const float* bc    = (const float*)d_in[13];
    const float* Wo    = (const float*)d_in[14];
    const float* bo    = (const float*)d_in[15];
    const int*   start = (const int*)d_in[16];
    float* ws  = (float*)d_ws;
    float* out = (float*)d_out;

    float*          xs   = ws + OFF_XS;
    unsigned short* xwq  = (unsigned short*)(ws + OFF_XW);
    unsigned short* WoT  = (unsigned short*)(ws + OFF_XW);   // aliases xwq (dead after recur)
    unsigned short* hbf  = (unsigned short*)(ws + OFF_HB);
    float*          psB  = ws + OFF_PS;
    float*          tlB  = ws + OFF_TL;
    unsigned int*   UQ8  = (unsigned int*)(ws + OFF_U8);
    float*          scB  = ws + OFF_SC;
    int*            tgtr = (int*)(ws + OFF_TGT);

    lstm_embed <<<(T * B * E + 255) / 256, 256, 0, stream>>>(x, emb, start, xs, out, tgtr);
    lstm_xw    <<<T, 256, 0, stream>>>(xs, xwq, Wi, Wf, Wog, Wc, bi, bf, bog, bc);
    lstm_umax  <<<4, 256, 0, stream>>>(Ui, Uf, Uog, Uc, scB);
    lstm_uq8   <<<(H / 4) * H / 256, 256, 0, stream>>>(Ui, Uf, Uog, Uc, scB, UQ8);
    lstm_recur_i8<<<B, 1024, 0, stream>>>(xwq, (const uint4*)UQ8, scB, hbf);
    lstm_wot   <<<dim3(V / 64, H / 64), 256, 0, stream>>>(Wo, WoT);
    lstm_logits_mfma<<<NVB, 512, 0, stream>>>(hbf, WoT, bo, tgtr, psB, tlB);
    lstm_lse   <<<NROW / 256, 256, 0, stream>>>(psB, tlB, out);
}